// Round 16
// baseline (207.977 us; speedup 1.0000x reference)
//
#include <hip/hip_runtime.h>
#include <math.h>

#define TWO_H 4096
#define HALF_H 2048
#define NGROUPS 8
#define BLOCK 256
#define WPB 4      // waves per block
#define GRID 2048  // 8192 waves; grid-stride interleaved (proven best mapping)

typedef int    vi4 __attribute__((ext_vector_type(4)));
typedef float  vf4 __attribute__((ext_vector_type(4)));
typedef __fp16 vh2 __attribute__((ext_vector_type(2)));

// R15 + deeper cross-row pipeline: next row's first FOUR chunks (half the
// row) prefetched before the reduce/store epilogue.
__global__ __launch_bounds__(BLOCK, 4) void swiglu_requant_kernel(
    const int* __restrict__ x,         // [N, 4096] int32
    const float* __restrict__ wscale,  // [G, 4096]
    const float* __restrict__ ascale,  // [N]
    const float* __restrict__ bias,    // [4096]
    const float* __restrict__ qscale,  // [G]
    const int* __restrict__ gindex,    // [G]
    int* __restrict__ out,             // [N, 2048] int32 (int8 values widened)
    int n_rows)
{
    const int lane   = threadIdx.x & 63;
    const int wid    = blockIdx.x * WPB + (threadIdx.x >> 6);
    const int nwaves = GRID * WPB;

    // group boundaries (cumsum), wave-uniform
    int cum[NGROUPS];
    {
        int c = 0;
#pragma unroll
        for (int g = 0; g < NGROUPS; ++g) { c += gindex[g]; cum[g] = c; }
    }

    int row = wid;
    if (row >= n_rows) return;

    const int lofs = lane * 4;

    // prime the pipeline: row's chunks 0..3 + ascale
    const int* xrow = x + (long)row * TWO_H;
    vi4 pg[4], pu[4];
#pragma unroll
    for (int c = 0; c < 4; ++c) {
        pg[c] = *(const vi4*)(xrow + c * 256 + lofs);
        pu[c] = *(const vi4*)(xrow + HALF_H + c * 256 + lofs);
    }
    float pa = ascale[row];

    while (true) {
        int gid = 0;
#pragma unroll
        for (int g = 0; g < NGROUPS; ++g) gid += (row >= cum[g]) ? 1 : 0;

        const float a_s = pa;
        const float q_s = qscale[gid];
        const float* wrow = wscale + (long)gid * TWO_H;

        vh2   o16[16];
        float lmax = 0.0f;

        auto do_chunk = [&](int c, vi4 g, vi4 u) {
            const int cg = c * 256 + lofs;
            vf4 wg = *(const vf4*)(wrow + cg);
            vf4 wu = *(const vf4*)(wrow + HALF_H + cg);
            vf4 bg = *(const vf4*)(bias + cg);
            vf4 bu = *(const vf4*)(bias + HALF_H + cg);

            float gi[4] = {(float)g.x, (float)g.y, (float)g.z, (float)g.w};
            float ui[4] = {(float)u.x, (float)u.y, (float)u.z, (float)u.w};
            float wgx[4] = {wg.x, wg.y, wg.z, wg.w};
            float wux[4] = {wu.x, wu.y, wu.z, wu.w};
            float bgx[4] = {bg.x, bg.y, bg.z, bg.w};
            float bux[4] = {bu.x, bu.y, bu.z, bu.w};

            float ov[4];
#pragma unroll
            for (int i = 0; i < 4; ++i) {
                float gv = (gi[i] + bgx[i]) * wgx[i] * a_s;
                float uv = (ui[i] + bux[i]) * wux[i] * a_s;
                float e  = __expf(-uv);
                float sv = uv * __builtin_amdgcn_rcpf(1.0f + e);  // silu(up)
                float o  = sv * gv * q_s;
                ov[i] = o;
                lmax = fmaxf(lmax, fabsf(o));
            }
            o16[c * 2]     = __builtin_amdgcn_cvt_pkrtz(ov[0], ov[1]);
            o16[c * 2 + 1] = __builtin_amdgcn_cvt_pkrtz(ov[2], ov[3]);
        };

        // chunks 0..3 from prefetched registers
#pragma unroll
        for (int c = 0; c < 4; ++c) do_chunk(c, pg[c], pu[c]);
        // chunks 4..7: load + compute
#pragma unroll
        for (int c = 4; c < 8; ++c) {
            const int cg = c * 256 + lofs;
            vi4 g = *(const vi4*)(xrow + cg);
            vi4 u = *(const vi4*)(xrow + HALF_H + cg);
            do_chunk(c, g, u);
        }

        // ---- prefetch next row's chunks 0..3 + ascale (in flight across epilogue)
        const int  nrow = row + nwaves;
        const bool hn   = (nrow < n_rows);
        const int* nx   = x + (long)(hn ? nrow : wid) * TWO_H;  // safe dummy addr
#pragma unroll
        for (int c = 0; c < 4; ++c) {
            pg[c] = *(const vi4*)(nx + c * 256 + lofs);
            pu[c] = *(const vi4*)(nx + HALF_H + c * 256 + lofs);
        }
        pa = ascale[hn ? nrow : wid];

        // ---- epilogue: reduce, scale, nt-stores
#pragma unroll
        for (int m = 1; m < 64; m <<= 1)
            lmax = fmaxf(lmax, __shfl_xor(lmax, m, 64));

        const float scale = 127.0f / lmax;

        int* orow = out + (long)row * HALF_H;
#pragma unroll
        for (int c = 0; c < 8; ++c) {
            const int co = c * 256 + lofs;
            float ov[4] = {(float)o16[c * 2].x,     (float)o16[c * 2].y,
                           (float)o16[c * 2 + 1].x, (float)o16[c * 2 + 1].y};
            int w[4];
#pragma unroll
            for (int i = 0; i < 4; ++i) {
                float v = ov[i] * scale;
                v = fminf(fmaxf(v, -128.0f), 127.0f);  // clip then round (matches ref)
                w[i] = (int)rintf(v);                   // round half-to-even
            }
            vi4 wv = {w[0], w[1], w[2], w[3]};
            __builtin_nontemporal_store(wv, (vi4*)(orow + co));
        }

        if (!hn) break;
        row  = nrow;
        xrow = nx;
    }
}

extern "C" void kernel_launch(void* const* d_in, const int* in_sizes, int n_in,
                              void* d_out, int out_size, void* d_ws, size_t ws_size,
                              hipStream_t stream) {
    const int*   x      = (const int*)d_in[0];
    const float* wscale = (const float*)d_in[1];
    const float* ascale = (const float*)d_in[2];
    const float* bias   = (const float*)d_in[3];
    const float* qscale = (const float*)d_in[4];
    const int*   gindex = (const int*)d_in[5];
    int* out = (int*)d_out;

    const int n_rows = in_sizes[0] / TWO_H;  // 32768

    swiglu_requant_kernel<<<GRID, BLOCK, 0, stream>>>(
        x, wscale, ascale, bias, qscale, gindex, out, n_rows);
}

// Round 17
// 199.256 us; speedup vs baseline: 1.0438x; 1.0438x over previous
//
#include <hip/hip_runtime.h>
#include <math.h>

#define TWO_H 4096
#define HALF_H 2048
#define NGROUPS 8
#define BLOCK 256
#define WPB 4      // waves per block
#define GRID 2048  // 8192 waves; grid-stride interleaved (proven best mapping)

typedef int    vi4 __attribute__((ext_vector_type(4)));
typedef float  vf4 __attribute__((ext_vector_type(4)));
typedef __fp16 vh2 __attribute__((ext_vector_type(2)));

// R15 + one more prefetch chunk (3 of 8): next row's first THREE chunks in
// flight across the reduce/store epilogue. (4 chunks spilled: R16 = 208us.)
__global__ __launch_bounds__(BLOCK, 4) void swiglu_requant_kernel(
    const int* __restrict__ x,         // [N, 4096] int32
    const float* __restrict__ wscale,  // [G, 4096]
    const float* __restrict__ ascale,  // [N]
    const float* __restrict__ bias,    // [4096]
    const float* __restrict__ qscale,  // [G]
    const int* __restrict__ gindex,    // [G]
    int* __restrict__ out,             // [N, 2048] int32 (int8 values widened)
    int n_rows)
{
    const int lane   = threadIdx.x & 63;
    const int wid    = blockIdx.x * WPB + (threadIdx.x >> 6);
    const int nwaves = GRID * WPB;

    // group boundaries (cumsum), wave-uniform
    int cum[NGROUPS];
    {
        int c = 0;
#pragma unroll
        for (int g = 0; g < NGROUPS; ++g) { c += gindex[g]; cum[g] = c; }
    }

    int row = wid;
    if (row >= n_rows) return;

    const int lofs = lane * 4;

    // prime the pipeline: row's chunks 0..2 + ascale
    const int* xrow = x + (long)row * TWO_H;
    vi4 pg[3], pu[3];
#pragma unroll
    for (int c = 0; c < 3; ++c) {
        pg[c] = *(const vi4*)(xrow + c * 256 + lofs);
        pu[c] = *(const vi4*)(xrow + HALF_H + c * 256 + lofs);
    }
    float pa = ascale[row];

    while (true) {
        int gid = 0;
#pragma unroll
        for (int g = 0; g < NGROUPS; ++g) gid += (row >= cum[g]) ? 1 : 0;

        const float a_s = pa;
        const float q_s = qscale[gid];
        const float* wrow = wscale + (long)gid * TWO_H;

        vh2   o16[16];
        float lmax = 0.0f;

        auto do_chunk = [&](int c, vi4 g, vi4 u) {
            const int cg = c * 256 + lofs;
            vf4 wg = *(const vf4*)(wrow + cg);
            vf4 wu = *(const vf4*)(wrow + HALF_H + cg);
            vf4 bg = *(const vf4*)(bias + cg);
            vf4 bu = *(const vf4*)(bias + HALF_H + cg);

            float gi[4] = {(float)g.x, (float)g.y, (float)g.z, (float)g.w};
            float ui[4] = {(float)u.x, (float)u.y, (float)u.z, (float)u.w};
            float wgx[4] = {wg.x, wg.y, wg.z, wg.w};
            float wux[4] = {wu.x, wu.y, wu.z, wu.w};
            float bgx[4] = {bg.x, bg.y, bg.z, bg.w};
            float bux[4] = {bu.x, bu.y, bu.z, bu.w};

            float ov[4];
#pragma unroll
            for (int i = 0; i < 4; ++i) {
                float gv = (gi[i] + bgx[i]) * wgx[i] * a_s;
                float uv = (ui[i] + bux[i]) * wux[i] * a_s;
                float e  = __expf(-uv);
                float sv = uv * __builtin_amdgcn_rcpf(1.0f + e);  // silu(up)
                float o  = sv * gv * q_s;
                ov[i] = o;
                lmax = fmaxf(lmax, fabsf(o));
            }
            o16[c * 2]     = __builtin_amdgcn_cvt_pkrtz(ov[0], ov[1]);
            o16[c * 2 + 1] = __builtin_amdgcn_cvt_pkrtz(ov[2], ov[3]);
        };

        // chunks 0..2 from prefetched registers
#pragma unroll
        for (int c = 0; c < 3; ++c) do_chunk(c, pg[c], pu[c]);
        // chunks 3..7: load + compute
#pragma unroll
        for (int c = 3; c < 8; ++c) {
            const int cg = c * 256 + lofs;
            vi4 g = *(const vi4*)(xrow + cg);
            vi4 u = *(const vi4*)(xrow + HALF_H + cg);
            do_chunk(c, g, u);
        }

        // ---- prefetch next row's chunks 0..2 + ascale (in flight across epilogue)
        const int  nrow = row + nwaves;
        const bool hn   = (nrow < n_rows);
        const int* nx   = x + (long)(hn ? nrow : wid) * TWO_H;  // safe dummy addr
#pragma unroll
        for (int c = 0; c < 3; ++c) {
            pg[c] = *(const vi4*)(nx + c * 256 + lofs);
            pu[c] = *(const vi4*)(nx + HALF_H + c * 256 + lofs);
        }
        pa = ascale[hn ? nrow : wid];

        // ---- epilogue: reduce, scale, nt-stores
#pragma unroll
        for (int m = 1; m < 64; m <<= 1)
            lmax = fmaxf(lmax, __shfl_xor(lmax, m, 64));

        const float scale = 127.0f / lmax;

        int* orow = out + (long)row * HALF_H;
#pragma unroll
        for (int c = 0; c < 8; ++c) {
            const int co = c * 256 + lofs;
            float ov[4] = {(float)o16[c * 2].x,     (float)o16[c * 2].y,
                           (float)o16[c * 2 + 1].x, (float)o16[c * 2 + 1].y};
            int w[4];
#pragma unroll
            for (int i = 0; i < 4; ++i) {
                float v = ov[i] * scale;
                v = fminf(fmaxf(v, -128.0f), 127.0f);  // clip then round (matches ref)
                w[i] = (int)rintf(v);                   // round half-to-even
            }
            vi4 wv = {w[0], w[1], w[2], w[3]};
            __builtin_nontemporal_store(wv, (vi4*)(orow + co));
        }

        if (!hn) break;
        row  = nrow;
        xrow = nx;
    }
}

extern "C" void kernel_launch(void* const* d_in, const int* in_sizes, int n_in,
                              void* d_out, int out_size, void* d_ws, size_t ws_size,
                              hipStream_t stream) {
    const int*   x      = (const int*)d_in[0];
    const float* wscale = (const float*)d_in[1];
    const float* ascale = (const float*)d_in[2];
    const float* bias   = (const float*)d_in[3];
    const float* qscale = (const float*)d_in[4];
    const int*   gindex = (const int*)d_in[5];
    int* out = (int*)d_out;

    const int n_rows = in_sizes[0] / TWO_H;  // 32768

    swiglu_requant_kernel<<<GRID, BLOCK, 0, stream>>>(
        x, wscale, ascale, bias, qscale, gindex, out, n_rows);
}

// Round 18
// 154.827 us; speedup vs baseline: 1.3433x; 1.2870x over previous
//
#include <hip/hip_runtime.h>
#include <math.h>

#define TWO_H 4096
#define HALF_H 2048
#define NGROUPS 8
#define BLOCK 256
#define WPB 4      // waves per block
#define GRID 2048  // 8192 waves; grid-stride interleaved (proven best mapping)

typedef int    vi4 __attribute__((ext_vector_type(4)));
typedef float  vf4 __attribute__((ext_vector_type(4)));
typedef __fp16 vh2 __attribute__((ext_vector_type(2)));

// CHAMPION (R15, 154.3us): wave-per-row grid-stride, no LDS, no barriers,
// f16-packed row buffer, nt-stores, 2-chunk cross-row prefetch (the spill-free
// max: 3 and 4 chunks both spill at the 128-VGPR cap -> 199/208us).
__global__ __launch_bounds__(BLOCK, 4) void swiglu_requant_kernel(
    const int* __restrict__ x,         // [N, 4096] int32
    const float* __restrict__ wscale,  // [G, 4096]
    const float* __restrict__ ascale,  // [N]
    const float* __restrict__ bias,    // [4096]
    const float* __restrict__ qscale,  // [G]
    const int* __restrict__ gindex,    // [G]
    int* __restrict__ out,             // [N, 2048] int32 (int8 values widened)
    int n_rows)
{
    const int lane   = threadIdx.x & 63;
    const int wid    = blockIdx.x * WPB + (threadIdx.x >> 6);
    const int nwaves = GRID * WPB;

    // group boundaries (cumsum), wave-uniform
    int cum[NGROUPS];
    {
        int c = 0;
#pragma unroll
        for (int g = 0; g < NGROUPS; ++g) { c += gindex[g]; cum[g] = c; }
    }

    int row = wid;
    if (row >= n_rows) return;

    const int lofs = lane * 4;

    // prime the pipeline: row's chunks 0,1 + ascale
    const int* xrow = x + (long)row * TWO_H;
    vi4 pg[2], pu[2];
    pg[0] = *(const vi4*)(xrow + lofs);
    pu[0] = *(const vi4*)(xrow + HALF_H + lofs);
    pg[1] = *(const vi4*)(xrow + 256 + lofs);
    pu[1] = *(const vi4*)(xrow + HALF_H + 256 + lofs);
    float pa = ascale[row];

    while (true) {
        int gid = 0;
#pragma unroll
        for (int g = 0; g < NGROUPS; ++g) gid += (row >= cum[g]) ? 1 : 0;

        const float a_s = pa;
        const float q_s = qscale[gid];
        const float* wrow = wscale + (long)gid * TWO_H;

        vh2   o16[16];
        float lmax = 0.0f;

        auto do_chunk = [&](int c, vi4 g, vi4 u) {
            const int cg = c * 256 + lofs;
            vf4 wg = *(const vf4*)(wrow + cg);
            vf4 wu = *(const vf4*)(wrow + HALF_H + cg);
            vf4 bg = *(const vf4*)(bias + cg);
            vf4 bu = *(const vf4*)(bias + HALF_H + cg);

            float gi[4] = {(float)g.x, (float)g.y, (float)g.z, (float)g.w};
            float ui[4] = {(float)u.x, (float)u.y, (float)u.z, (float)u.w};
            float wgx[4] = {wg.x, wg.y, wg.z, wg.w};
            float wux[4] = {wu.x, wu.y, wu.z, wu.w};
            float bgx[4] = {bg.x, bg.y, bg.z, bg.w};
            float bux[4] = {bu.x, bu.y, bu.z, bu.w};

            float ov[4];
#pragma unroll
            for (int i = 0; i < 4; ++i) {
                float gv = (gi[i] + bgx[i]) * wgx[i] * a_s;
                float uv = (ui[i] + bux[i]) * wux[i] * a_s;
                float e  = __expf(-uv);
                float sv = uv * __builtin_amdgcn_rcpf(1.0f + e);  // silu(up)
                float o  = sv * gv * q_s;
                ov[i] = o;
                lmax = fmaxf(lmax, fabsf(o));
            }
            o16[c * 2]     = __builtin_amdgcn_cvt_pkrtz(ov[0], ov[1]);
            o16[c * 2 + 1] = __builtin_amdgcn_cvt_pkrtz(ov[2], ov[3]);
        };

        // chunks 0,1 from prefetched registers
        do_chunk(0, pg[0], pu[0]);
        do_chunk(1, pg[1], pu[1]);
        // chunks 2..7: load + compute
#pragma unroll
        for (int c = 2; c < 8; ++c) {
            const int cg = c * 256 + lofs;
            vi4 g = *(const vi4*)(xrow + cg);
            vi4 u = *(const vi4*)(xrow + HALF_H + cg);
            do_chunk(c, g, u);
        }

        // ---- prefetch next row's chunks 0,1 + ascale (in flight across epilogue)
        const int  nrow = row + nwaves;
        const bool hn   = (nrow < n_rows);
        const int* nx   = x + (long)(hn ? nrow : wid) * TWO_H;  // safe dummy addr
        pg[0] = *(const vi4*)(nx + lofs);
        pu[0] = *(const vi4*)(nx + HALF_H + lofs);
        pg[1] = *(const vi4*)(nx + 256 + lofs);
        pu[1] = *(const vi4*)(nx + HALF_H + 256 + lofs);
        pa    = ascale[hn ? nrow : wid];

        // ---- epilogue: reduce, scale, nt-stores
#pragma unroll
        for (int m = 1; m < 64; m <<= 1)
            lmax = fmaxf(lmax, __shfl_xor(lmax, m, 64));

        const float scale = 127.0f / lmax;

        int* orow = out + (long)row * HALF_H;
#pragma unroll
        for (int c = 0; c < 8; ++c) {
            const int co = c * 256 + lofs;
            float ov[4] = {(float)o16[c * 2].x,     (float)o16[c * 2].y,
                           (float)o16[c * 2 + 1].x, (float)o16[c * 2 + 1].y};
            int w[4];
#pragma unroll
            for (int i = 0; i < 4; ++i) {
                float v = ov[i] * scale;
                v = fminf(fmaxf(v, -128.0f), 127.0f);  // clip then round (matches ref)
                w[i] = (int)rintf(v);                   // round half-to-even
            }
            vi4 wv = {w[0], w[1], w[2], w[3]};
            __builtin_nontemporal_store(wv, (vi4*)(orow + co));
        }

        if (!hn) break;
        row  = nrow;
        xrow = nx;
    }
}

extern "C" void kernel_launch(void* const* d_in, const int* in_sizes, int n_in,
                              void* d_out, int out_size, void* d_ws, size_t ws_size,
                              hipStream_t stream) {
    const int*   x      = (const int*)d_in[0];
    const float* wscale = (const float*)d_in[1];
    const float* ascale = (const float*)d_in[2];
    const float* bias   = (const float*)d_in[3];
    const float* qscale = (const float*)d_in[4];
    const int*   gindex = (const int*)d_in[5];
    int* out = (int*)d_out;

    const int n_rows = in_sizes[0] / TWO_H;  // 32768

    swiglu_requant_kernel<<<GRID, BLOCK, 0, stream>>>(
        x, wscale, ascale, bias, qscale, gindex, out, n_rows);
}